// Round 3
// baseline (336.168 us; speedup 1.0000x reference)
//
#include <hip/hip_runtime.h>
#include <stdint.h>

#define DH 128   // D_IN == H == 128
#define NB 30    // num bases
#define NR 8     // num relations

typedef short bf16x8 __attribute__((ext_vector_type(8)));   // 8 bf16 = 4 VGPRs
typedef float f32x4 __attribute__((ext_vector_type(4)));

static __device__ __forceinline__ unsigned short f2bf(float f) {
    unsigned u = __float_as_uint(f);
    u += 0x7fffu + ((u >> 16) & 1u);   // round-to-nearest-even
    return (unsigned short)(u >> 16);
}

// ---------- X fp32 -> bf16 ----------
__global__ __launch_bounds__(256) void k_cvtx(const float* __restrict__ x,
                                              unsigned short* __restrict__ xbf, int n4) {
    int i = blockIdx.x * blockDim.x + threadIdx.x;
    if (i < n4) {
        float4 v = ((const float4*)x)[i];
        ushort4 u;
        u.x = f2bf(v.x); u.y = f2bf(v.y); u.z = f2bf(v.z); u.w = f2bf(v.w);
        ((ushort4*)xbf)[i] = u;
    }
}

// ---------- weight prep (transposed bf16) ----------
// y<9:  wallT[y][o][i] = sum_b comp[y,b]*basis[b,i,o]   (y==8 -> root[i][o])
// y==9: WT2[0][n][k] = wrel[k][n];  y==10: WT2[1][n][k] = wroot2[k][n]
__global__ __launch_bounds__(128) void k_wprep(const float* __restrict__ comp,
                                               const float* __restrict__ basis,
                                               const float* __restrict__ root,
                                               const float* __restrict__ wrel,
                                               const float* __restrict__ wroot2,
                                               unsigned short* __restrict__ wallT,
                                               unsigned short* __restrict__ WT2) {
    int o = threadIdx.x;    // 0..127
    int i = blockIdx.x;     // 0..127
    int y = blockIdx.y;     // 0..10
    if (y < NR) {
        float s = 0.f;
        #pragma unroll
        for (int b = 0; b < NB; ++b)
            s += comp[y * NB + b] * basis[((size_t)b * DH + i) * DH + o];
        wallT[((size_t)y * DH + o) * DH + i] = f2bf(s);
    } else if (y == NR) {
        wallT[((size_t)NR * DH + o) * DH + i] = f2bf(root[i * DH + o]);
    } else {
        const float* W = (y == NR + 2) ? wroot2 : wrel;
        WT2[((size_t)(y - NR - 1) * DH + o) * DH + i] = f2bf(W[i * DH + o]);
    }
}

// ---------- CSR build ----------
__global__ void k_hist(const int* __restrict__ dst, int E, int* __restrict__ deg) {
    int e = blockIdx.x * blockDim.x + threadIdx.x;
    if (e < E) atomicAdd(&deg[dst[e]], 1);
}

// single-block exclusive scan of deg[0..n-1] -> offsets[0..n] (offsets[n]=total)
__global__ __launch_bounds__(1024) void k_scan(const int* __restrict__ deg, int n,
                                               int* __restrict__ offsets) {
    __shared__ int wsum[16];
    const int tid = threadIdx.x;
    const int lane = tid & 63, wv = tid >> 6;
    int carry = 0;
    for (int base = 0; base <= n; base += 1024) {
        int i = base + tid;
        int v = (i < n) ? deg[i] : 0;
        int x = v;
        #pragma unroll
        for (int d = 1; d < 64; d <<= 1) {
            int t = __shfl_up(x, d, 64);
            if (lane >= d) x += t;
        }
        if (lane == 63) wsum[wv] = x;
        __syncthreads();
        if (wv == 0) {
            int y = (lane < 16) ? wsum[lane] : 0;
            #pragma unroll
            for (int d = 1; d < 16; d <<= 1) {
                int t = __shfl_up(y, d, 64);
                if (lane >= d) y += t;
            }
            if (lane < 16) wsum[lane] = y;
        }
        __syncthreads();
        int wbase = (wv == 0) ? 0 : wsum[wv - 1];
        if (i <= n) offsets[i] = carry + wbase + x - v;
        int tot = wsum[15];
        __syncthreads();
        carry += tot;
    }
}

__global__ void k_scatter(const int* __restrict__ src, const int* __restrict__ dstA,
                          const int* __restrict__ etype, int E,
                          const int* __restrict__ offsets, int* __restrict__ cursor,
                          unsigned* __restrict__ sorted) {
    int e = blockIdx.x * blockDim.x + threadIdx.x;
    if (e >= E) return;
    int d = dstA[e];
    int pos = offsets[d] + atomicAdd(&cursor[d], 1);
    sorted[pos] = (unsigned)src[e] | ((unsigned)etype[e] << 17);  // src<2^17, type<8
}

// ---------- MFMA GEMM1: 128x128 tile, K=128, grid (ceil(N/128), 9) ----------
// r<8: xw[r] = Xbf @ W_r  (bf16). r==8: hb = Xbf @ root + bias1 (bf16)
__global__ __launch_bounds__(256) void k_gemm1m(const unsigned short* __restrict__ Xbf,
                                                const unsigned short* __restrict__ wallT,
                                                const float* __restrict__ bias1,
                                                int Nn,
                                                unsigned short* __restrict__ xw,
                                                unsigned short* __restrict__ hb) {
    __shared__ __align__(16) unsigned short As[128][136];  // [m][k], +8 pad
    __shared__ __align__(16) unsigned short Bs[128][136];  // [n][k], +8 pad
    const int tid = threadIdx.x;
    const int wave = tid >> 6, lane = tid & 63;
    const int r = blockIdx.y;
    const int rowbase = blockIdx.x * 128;
    const unsigned short* WT = wallT + (size_t)r * DH * DH;

    #pragma unroll
    for (int it = 0; it < 8; ++it) {
        int c = it * 256 + tid;
        int row = c >> 4, col = c & 15;
        int rg = rowbase + row; if (rg >= Nn) rg = Nn - 1;
        *(uint4*)&As[row][col * 8] = *(const uint4*)&Xbf[(size_t)rg * DH + col * 8];
        *(uint4*)&Bs[row][col * 8] = *(const uint4*)&WT[(size_t)row * DH + col * 8];
    }
    __syncthreads();

    f32x4 acc[2][8];
    #pragma unroll
    for (int mt = 0; mt < 2; ++mt)
        #pragma unroll
        for (int nt = 0; nt < 8; ++nt) acc[mt][nt] = (f32x4)0.f;

    const int lq = lane >> 4, lr = lane & 15;
    #pragma unroll
    for (int ks = 0; ks < 4; ++ks) {
        const int ko = ks * 32 + lq * 8;
        bf16x8 a0 = *(const bf16x8*)&As[wave * 32 + lr][ko];
        bf16x8 a1 = *(const bf16x8*)&As[wave * 32 + 16 + lr][ko];
        #pragma unroll
        for (int nt = 0; nt < 8; ++nt) {
            bf16x8 b = *(const bf16x8*)&Bs[nt * 16 + lr][ko];
            acc[0][nt] = __builtin_amdgcn_mfma_f32_16x16x32_bf16(a0, b, acc[0][nt], 0, 0, 0);
            acc[1][nt] = __builtin_amdgcn_mfma_f32_16x16x32_bf16(a1, b, acc[1][nt], 0, 0, 0);
        }
    }

    // bias (only for r==8), then repack C-layout -> canonical bf16 rows via As
    float bv[8];
    #pragma unroll
    for (int nt = 0; nt < 8; ++nt) bv[nt] = (r == NR) ? bias1[nt * 16 + lr] : 0.f;
    #pragma unroll
    for (int mt = 0; mt < 2; ++mt)
        #pragma unroll
        for (int nt = 0; nt < 8; ++nt)
            #pragma unroll
            for (int reg = 0; reg < 4; ++reg) {
                int ml = wave * 32 + mt * 16 + lq * 4 + reg;   // own slab only
                As[ml][nt * 16 + lr] = f2bf(acc[mt][nt][reg] + bv[nt]);
            }
    __syncthreads();
    unsigned short* dst = (r < NR) ? xw + ((size_t)r * Nn + rowbase) * DH
                                   : hb + (size_t)rowbase * DH;
    #pragma unroll
    for (int it = 0; it < 8; ++it) {
        int c = it * 256 + tid;
        int row = c >> 4, col = c & 15;
        if (rowbase + row < Nn)
            *(uint4*)&dst[(size_t)row * DH + col * 8] = *(uint4*)&As[row][col * 8];
    }
}

// ---------- pass-1 aggregation: one wave per dst, 8-edge unrolled gather ----------
// hbf[dst] = bf16( hb[dst] + (1/deg) * sum_e xw[type_e][src_e] )
__global__ __launch_bounds__(256) void k_agg1(const int* __restrict__ offsets,
                                              const unsigned* __restrict__ sorted,
                                              const unsigned* __restrict__ xw32,
                                              const unsigned* __restrict__ hb32,
                                              int Nn, unsigned* __restrict__ hbf) {
    int w = (blockIdx.x * blockDim.x + threadIdx.x) >> 6;
    if (w >= Nn) return;
    int lane = threadIdx.x & 63;
    int s = offsets[w], e = offsets[w + 1];
    float ax = 0.f, ay = 0.f;
    for (int p = s; p < e; p += 8) {
        unsigned pk[8]; float m[8];
        #pragma unroll
        for (int j = 0; j < 8; ++j) {
            int q = p + j; bool v = q < e;
            pk[j] = sorted[v ? q : e - 1];
            m[j] = v ? 1.f : 0.f;
        }
        unsigned u[8];
        #pragma unroll
        for (int j = 0; j < 8; ++j)
            u[j] = xw32[((size_t)(pk[j] >> 17) * Nn + (pk[j] & 0x1FFFFu)) * 64 + lane];
        #pragma unroll
        for (int j = 0; j < 8; ++j) {
            ax = fmaf(m[j], __uint_as_float(u[j] << 16), ax);
            ay = fmaf(m[j], __uint_as_float(u[j] & 0xffff0000u), ay);
        }
    }
    float invd = 1.0f / fmaxf((float)(e - s), 1.0f);
    unsigned hv = hb32[(size_t)w * 64 + lane];
    float hx = __uint_as_float(hv << 16) + ax * invd;
    float hy = __uint_as_float(hv & 0xffff0000u) + ay * invd;
    hbf[(size_t)w * 64 + lane] = (unsigned)f2bf(hx) | ((unsigned)f2bf(hy) << 16);
}

// ---------- fused agg2 + GEMM2: out = (gather-sum hbf)@wrel + hbf@wroot2 + bias2 ----------
__global__ __launch_bounds__(256) void k_agg2gemm2(const int* __restrict__ offsets,
                                                   const unsigned* __restrict__ sorted,
                                                   const unsigned* __restrict__ hbf32,
                                                   const unsigned short* __restrict__ WT2,
                                                   const float* __restrict__ bias2,
                                                   int Nn, float* __restrict__ out) {
    __shared__ __align__(16) unsigned short As[128][136];
    __shared__ __align__(16) unsigned short Bs[128][136];
    const int tid = threadIdx.x;
    const int wave = tid >> 6, lane = tid & 63;
    const int rowbase = blockIdx.x * 128;
    const int lq = lane >> 4, lr = lane & 15;

    // stage Bs = wrel^T
    #pragma unroll
    for (int it = 0; it < 8; ++it) {
        int c = it * 256 + tid;
        int row = c >> 4, col = c & 15;
        *(uint4*)&Bs[row][col * 8] = *(const uint4*)&WT2[(size_t)row * DH + col * 8];
    }
    // phase-0 A: gather nbr rows (sum of hbf[src]) straight into As as bf16
    for (int i = 0; i < 32; ++i) {
        int node = rowbase + wave * 32 + i;
        float ax = 0.f, ay = 0.f;
        if (node < Nn) {
            int s = offsets[node], e = offsets[node + 1];
            for (int p = s; p < e; p += 8) {
                unsigned pk[8]; float m[8];
                #pragma unroll
                for (int j = 0; j < 8; ++j) {
                    int q = p + j; bool v = q < e;
                    pk[j] = sorted[v ? q : e - 1];
                    m[j] = v ? 1.f : 0.f;
                }
                unsigned u[8];
                #pragma unroll
                for (int j = 0; j < 8; ++j)
                    u[j] = hbf32[(size_t)(pk[j] & 0x1FFFFu) * 64 + lane];
                #pragma unroll
                for (int j = 0; j < 8; ++j) {
                    ax = fmaf(m[j], __uint_as_float(u[j] << 16), ax);
                    ay = fmaf(m[j], __uint_as_float(u[j] & 0xffff0000u), ay);
                }
            }
        }
        *(unsigned*)&As[wave * 32 + i][lane * 2] = (unsigned)f2bf(ax) | ((unsigned)f2bf(ay) << 16);
    }
    __syncthreads();

    f32x4 acc[2][8];
    #pragma unroll
    for (int mt = 0; mt < 2; ++mt)
        #pragma unroll
        for (int nt = 0; nt < 8; ++nt) acc[mt][nt] = (f32x4)0.f;

    #pragma unroll
    for (int ks = 0; ks < 4; ++ks) {
        const int ko = ks * 32 + lq * 8;
        bf16x8 a0 = *(const bf16x8*)&As[wave * 32 + lr][ko];
        bf16x8 a1 = *(const bf16x8*)&As[wave * 32 + 16 + lr][ko];
        #pragma unroll
        for (int nt = 0; nt < 8; ++nt) {
            bf16x8 b = *(const bf16x8*)&Bs[nt * 16 + lr][ko];
            acc[0][nt] = __builtin_amdgcn_mfma_f32_16x16x32_bf16(a0, b, acc[0][nt], 0, 0, 0);
            acc[1][nt] = __builtin_amdgcn_mfma_f32_16x16x32_bf16(a1, b, acc[1][nt], 0, 0, 0);
        }
    }
    __syncthreads();

    // phase-1: As = hbf rows (canonical), Bs = wroot2^T
    const unsigned short* hbfs = (const unsigned short*)hbf32;
    #pragma unroll
    for (int it = 0; it < 8; ++it) {
        int c = it * 256 + tid;
        int row = c >> 4, col = c & 15;
        int rg = rowbase + row; if (rg >= Nn) rg = Nn - 1;
        *(uint4*)&As[row][col * 8] = *(const uint4*)&hbfs[(size_t)rg * DH + col * 8];
        *(uint4*)&Bs[row][col * 8] = *(const uint4*)&WT2[(size_t)(DH + row) * DH + col * 8];
    }
    __syncthreads();
    #pragma unroll
    for (int ks = 0; ks < 4; ++ks) {
        const int ko = ks * 32 + lq * 8;
        bf16x8 a0 = *(const bf16x8*)&As[wave * 32 + lr][ko];
        bf16x8 a1 = *(const bf16x8*)&As[wave * 32 + 16 + lr][ko];
        #pragma unroll
        for (int nt = 0; nt < 8; ++nt) {
            bf16x8 b = *(const bf16x8*)&Bs[nt * 16 + lr][ko];
            acc[0][nt] = __builtin_amdgcn_mfma_f32_16x16x32_bf16(a0, b, acc[0][nt], 0, 0, 0);
            acc[1][nt] = __builtin_amdgcn_mfma_f32_16x16x32_bf16(a1, b, acc[1][nt], 0, 0, 0);
        }
    }

    float bv[8];
    #pragma unroll
    for (int nt = 0; nt < 8; ++nt) bv[nt] = bias2[nt * 16 + lr];
    #pragma unroll
    for (int mt = 0; mt < 2; ++mt)
        #pragma unroll
        for (int nt = 0; nt < 8; ++nt)
            #pragma unroll
            for (int reg = 0; reg < 4; ++reg) {
                int m = rowbase + wave * 32 + mt * 16 + lq * 4 + reg;
                if (m < Nn) out[(size_t)m * DH + nt * 16 + lr] = acc[mt][nt][reg] + bv[nt];
            }
}

extern "C" void kernel_launch(void* const* d_in, const int* in_sizes, int n_in,
                              void* d_out, int out_size, void* d_ws, size_t ws_size,
                              hipStream_t stream) {
    const float* x      = (const float*)d_in[0];
    const int*   eidx   = (const int*)d_in[1];
    // d_in[2] = edge_norm: unused by the reference computation
    const int*   etype  = (const int*)d_in[3];
    const float* basis  = (const float*)d_in[4];
    const float* comp   = (const float*)d_in[5];
    const float* root   = (const float*)d_in[6];
    const float* bias1  = (const float*)d_in[7];
    const float* wrel   = (const float*)d_in[8];
    const float* wroot2 = (const float*)d_in[9];
    const float* bias2  = (const float*)d_in[10];
    float* out = (float*)d_out;

    const int N = in_sizes[0] / DH;    // 40000
    const int E = in_sizes[3];         // 640000
    const int* srcA = eidx;
    const int* dstA = eidx + E;

    char* ws = (char*)d_ws;
    size_t off = 0;
    auto alloc = [&](size_t bytes) -> void* {
        void* p = (void*)(ws + off);
        off += (bytes + 255) & ~(size_t)255;
        return p;
    };
    int* deg           = (int*)alloc((size_t)N * 4);      // N*4 divisible by 256
    int* cursor        = (int*)alloc((size_t)N * 4);      // adjacent to deg
    int* offsets       = (int*)alloc((size_t)(N + 1) * 4);
    unsigned* sorted   = (unsigned*)alloc((size_t)E * 4);
    unsigned short* wallT = (unsigned short*)alloc((size_t)(NR + 1) * DH * DH * 2);
    unsigned short* WT2   = (unsigned short*)alloc((size_t)2 * DH * DH * 2);
    unsigned short* Xbf   = (unsigned short*)alloc((size_t)N * DH * 2);
    unsigned short* xw    = (unsigned short*)alloc((size_t)NR * N * DH * 2);
    unsigned short* hb    = (unsigned short*)alloc((size_t)N * DH * 2);
    unsigned* hbf      = (unsigned*)alloc((size_t)N * (DH / 2) * 4);
    (void)ws_size; (void)n_in; (void)out_size;

    hipMemsetAsync(deg, 0, (size_t)N * 8, stream);  // deg + cursor (contiguous)

    k_cvtx<<<(N * DH / 4 + 255) / 256, 256, 0, stream>>>(x, Xbf, N * DH / 4);
    k_wprep<<<dim3(DH, NR + 3), DH, 0, stream>>>(comp, basis, root, wrel, wroot2, wallT, WT2);
    k_hist<<<(E + 255) / 256, 256, 0, stream>>>(dstA, E, deg);
    k_scan<<<1, 1024, 0, stream>>>(deg, N, offsets);
    k_scatter<<<(E + 255) / 256, 256, 0, stream>>>(srcA, dstA, etype, E, offsets, cursor, sorted);

    const int gx = (N + 127) / 128;
    k_gemm1m<<<dim3(gx, NR + 1), 256, 0, stream>>>(Xbf, wallT, bias1, N, xw, hb);
    k_agg1<<<(N * 64) / 256, 256, 0, stream>>>(offsets, sorted, (const unsigned*)xw,
                                               (const unsigned*)hb, N, hbf);
    k_agg2gemm2<<<gx, 256, 0, stream>>>(offsets, sorted, hbf, WT2, bias2, N, out);
}

// Round 4
// 267.027 us; speedup vs baseline: 1.2589x; 1.2589x over previous
//
#include <hip/hip_runtime.h>
#include <stdint.h>

#define DH 128   // D_IN == H == 128
#define NB 30    // num bases
#define NR 8     // num relations

typedef short bf16x8 __attribute__((ext_vector_type(8)));   // 8 bf16 = 4 VGPRs
typedef float f32x4 __attribute__((ext_vector_type(4)));

static __device__ __forceinline__ unsigned short f2bf(float f) {
    unsigned u = __float_as_uint(f);
    u += 0x7fffu + ((u >> 16) & 1u);   // round-to-nearest-even
    return (unsigned short)(u >> 16);
}

// ---------- X fp32 -> bf16 ----------
__global__ __launch_bounds__(256) void k_cvtx(const float* __restrict__ x,
                                              unsigned short* __restrict__ xbf, int n4) {
    int i = blockIdx.x * blockDim.x + threadIdx.x;
    if (i < n4) {
        float4 v = ((const float4*)x)[i];
        ushort4 u;
        u.x = f2bf(v.x); u.y = f2bf(v.y); u.z = f2bf(v.z); u.w = f2bf(v.w);
        ((ushort4*)xbf)[i] = u;
    }
}

// ---------- weight prep (transposed bf16) ----------
__global__ __launch_bounds__(128) void k_wprep(const float* __restrict__ comp,
                                               const float* __restrict__ basis,
                                               const float* __restrict__ root,
                                               const float* __restrict__ wrel,
                                               const float* __restrict__ wroot2,
                                               unsigned short* __restrict__ wallT,
                                               unsigned short* __restrict__ WT2) {
    int o = threadIdx.x;    // 0..127
    int i = blockIdx.x;     // 0..127
    int y = blockIdx.y;     // 0..10
    if (y < NR) {
        float s = 0.f;
        #pragma unroll
        for (int b = 0; b < NB; ++b)
            s += comp[y * NB + b] * basis[((size_t)b * DH + i) * DH + o];
        wallT[((size_t)y * DH + o) * DH + i] = f2bf(s);
    } else if (y == NR) {
        wallT[((size_t)NR * DH + o) * DH + i] = f2bf(root[i * DH + o]);
    } else {
        const float* W = (y == NR + 2) ? wroot2 : wrel;
        WT2[((size_t)(y - NR - 1) * DH + o) * DH + i] = f2bf(W[i * DH + o]);
    }
}

// ---------- CSR build ----------
__global__ void k_hist(const int* __restrict__ dst, int E, int* __restrict__ deg) {
    int e = blockIdx.x * blockDim.x + threadIdx.x;
    if (e < E) atomicAdd(&deg[dst[e]], 1);
}

__global__ __launch_bounds__(1024) void k_scan1(const int* __restrict__ deg, int n, int total_n,
                                                int* __restrict__ offsets, int* __restrict__ partial) {
    __shared__ int s[1024];
    int tid = threadIdx.x;
    int i = blockIdx.x * 1024 + tid;
    int v = (i < n) ? deg[i] : 0;
    s[tid] = v;
    __syncthreads();
    for (int off = 1; off < 1024; off <<= 1) {
        int t = (tid >= off) ? s[tid - off] : 0;
        __syncthreads();
        s[tid] += t;
        __syncthreads();
    }
    if (i < total_n) offsets[i] = s[tid] - v;   // exclusive
    if (tid == 1023) partial[blockIdx.x] = s[1023];
}

__global__ void k_scan2(int* __restrict__ partial, int nb) {
    if (threadIdx.x == 0) {
        int run = 0;
        for (int b = 0; b < nb; ++b) { int t = partial[b]; partial[b] = run; run += t; }
    }
}

__global__ __launch_bounds__(1024) void k_scan3(int* __restrict__ offsets,
                                                const int* __restrict__ partial, int total_n) {
    int i = blockIdx.x * 1024 + threadIdx.x;
    if (i < total_n) offsets[i] += partial[blockIdx.x];
}

__global__ void k_scatter(const int* __restrict__ src, const int* __restrict__ dstA,
                          const int* __restrict__ etype, int E,
                          const int* __restrict__ offsets, int* __restrict__ cursor,
                          unsigned* __restrict__ sorted) {
    int e = blockIdx.x * blockDim.x + threadIdx.x;
    if (e >= E) return;
    int d = dstA[e];
    int pos = offsets[d] + atomicAdd(&cursor[d], 1);
    sorted[pos] = (unsigned)src[e] | ((unsigned)etype[e] << 17);  // src<2^17, type<8
}

// ---------- MFMA GEMM1: 128x128 tile, K=128, grid (ceil(N/128), 9) ----------
// r<8: xw[r] = Xbf @ W_r  (bf16). r==8: hb = Xbf @ root + bias1 (bf16)
__global__ __launch_bounds__(256) void k_gemm1m(const unsigned short* __restrict__ Xbf,
                                                const unsigned short* __restrict__ wallT,
                                                const float* __restrict__ bias1,
                                                int Nn,
                                                unsigned short* __restrict__ xw,
                                                unsigned short* __restrict__ hb) {
    __shared__ __align__(16) unsigned short As[128][136];  // [m][k], +8 pad
    __shared__ __align__(16) unsigned short Bs[128][136];  // [n][k], +8 pad
    const int tid = threadIdx.x;
    const int wave = tid >> 6, lane = tid & 63;
    const int r = blockIdx.y;
    const int rowbase = blockIdx.x * 128;
    const unsigned short* WT = wallT + (size_t)r * DH * DH;

    #pragma unroll
    for (int it = 0; it < 8; ++it) {
        int c = it * 256 + tid;
        int row = c >> 4, col = c & 15;
        int rg = rowbase + row; if (rg >= Nn) rg = Nn - 1;
        *(uint4*)&As[row][col * 8] = *(const uint4*)&Xbf[(size_t)rg * DH + col * 8];
        *(uint4*)&Bs[row][col * 8] = *(const uint4*)&WT[(size_t)row * DH + col * 8];
    }
    __syncthreads();

    f32x4 acc[2][8];
    #pragma unroll
    for (int mt = 0; mt < 2; ++mt)
        #pragma unroll
        for (int nt = 0; nt < 8; ++nt) acc[mt][nt] = (f32x4)0.f;

    const int lq = lane >> 4, lr = lane & 15;
    #pragma unroll
    for (int ks = 0; ks < 4; ++ks) {
        const int ko = ks * 32 + lq * 8;
        bf16x8 a0 = *(const bf16x8*)&As[wave * 32 + lr][ko];
        bf16x8 a1 = *(const bf16x8*)&As[wave * 32 + 16 + lr][ko];
        #pragma unroll
        for (int nt = 0; nt < 8; ++nt) {
            bf16x8 b = *(const bf16x8*)&Bs[nt * 16 + lr][ko];
            acc[0][nt] = __builtin_amdgcn_mfma_f32_16x16x32_bf16(a0, b, acc[0][nt], 0, 0, 0);
            acc[1][nt] = __builtin_amdgcn_mfma_f32_16x16x32_bf16(a1, b, acc[1][nt], 0, 0, 0);
        }
    }

    float bv[8];
    #pragma unroll
    for (int nt = 0; nt < 8; ++nt) bv[nt] = (r == NR) ? bias1[nt * 16 + lr] : 0.f;
    #pragma unroll
    for (int mt = 0; mt < 2; ++mt)
        #pragma unroll
        for (int nt = 0; nt < 8; ++nt)
            #pragma unroll
            for (int reg = 0; reg < 4; ++reg) {
                int ml = wave * 32 + mt * 16 + lq * 4 + reg;   // own slab only
                As[ml][nt * 16 + lr] = f2bf(acc[mt][nt][reg] + bv[nt]);
            }
    __syncthreads();
    unsigned short* dst = (r < NR) ? xw + ((size_t)r * Nn + rowbase) * DH
                                   : hb + (size_t)rowbase * DH;
    #pragma unroll
    for (int it = 0; it < 8; ++it) {
        int c = it * 256 + tid;
        int row = c >> 4, col = c & 15;
        if (rowbase + row < Nn)
            *(uint4*)&dst[(size_t)row * DH + col * 8] = *(uint4*)&As[row][col * 8];
    }
}

// ---------- pass-1 aggregation: one wave per dst, 16-edge unrolled gather ----------
// hbf[dst] = bf16( hb[dst] + (1/deg) * sum_e xw[type_e][src_e] )
__global__ __launch_bounds__(256) void k_agg1(const int* __restrict__ offsets,
                                              const unsigned* __restrict__ sorted,
                                              const unsigned* __restrict__ xw32,
                                              const unsigned* __restrict__ hb32,
                                              int Nn, unsigned* __restrict__ hbf) {
    int w = (blockIdx.x * blockDim.x + threadIdx.x) >> 6;
    if (w >= Nn) return;
    int lane = threadIdx.x & 63;
    int s = offsets[w], e = offsets[w + 1];
    float ax = 0.f, ay = 0.f;
    for (int p = s; p < e; p += 16) {
        unsigned pk[16]; float m[16];
        #pragma unroll
        for (int j = 0; j < 16; ++j) {
            int q = p + j; bool v = q < e;
            pk[j] = sorted[v ? q : e - 1];
            m[j] = v ? 1.f : 0.f;
        }
        unsigned u[16];
        #pragma unroll
        for (int j = 0; j < 16; ++j)
            u[j] = xw32[((size_t)(pk[j] >> 17) * Nn + (pk[j] & 0x1FFFFu)) * 64 + lane];
        #pragma unroll
        for (int j = 0; j < 16; ++j) {
            ax = fmaf(m[j], __uint_as_float(u[j] << 16), ax);
            ay = fmaf(m[j], __uint_as_float(u[j] & 0xffff0000u), ay);
        }
    }
    float invd = 1.0f / fmaxf((float)(e - s), 1.0f);
    unsigned hv = hb32[(size_t)w * 64 + lane];
    float hx = __uint_as_float(hv << 16) + ax * invd;
    float hy = __uint_as_float(hv & 0xffff0000u) + ay * invd;
    hbf[(size_t)w * 64 + lane] = (unsigned)f2bf(hx) | ((unsigned)f2bf(hy) << 16);
}

// ---------- pass-2 aggregation: nbrbf[dst] = bf16( sum_e hbf[src_e] ) ----------
__global__ __launch_bounds__(256) void k_agg2(const int* __restrict__ offsets,
                                              const unsigned* __restrict__ sorted,
                                              const unsigned* __restrict__ hbf32,
                                              int Nn, unsigned* __restrict__ nbrbf) {
    int w = (blockIdx.x * blockDim.x + threadIdx.x) >> 6;
    if (w >= Nn) return;
    int lane = threadIdx.x & 63;
    int s = offsets[w], e = offsets[w + 1];
    float ax = 0.f, ay = 0.f;
    for (int p = s; p < e; p += 16) {
        unsigned pk[16]; float m[16];
        #pragma unroll
        for (int j = 0; j < 16; ++j) {
            int q = p + j; bool v = q < e;
            pk[j] = sorted[v ? q : e - 1];
            m[j] = v ? 1.f : 0.f;
        }
        unsigned u[16];
        #pragma unroll
        for (int j = 0; j < 16; ++j)
            u[j] = hbf32[(size_t)(pk[j] & 0x1FFFFu) * 64 + lane];
        #pragma unroll
        for (int j = 0; j < 16; ++j) {
            ax = fmaf(m[j], __uint_as_float(u[j] << 16), ax);
            ay = fmaf(m[j], __uint_as_float(u[j] & 0xffff0000u), ay);
        }
    }
    nbrbf[(size_t)w * 64 + lane] = (unsigned)f2bf(ax) | ((unsigned)f2bf(ay) << 16);
}

// ---------- MFMA GEMM2: out = nbr@w_rel + h@w_root2 + bias2 (K=256 in 2 phases) ----------
__global__ __launch_bounds__(256) void k_gemm2m(const unsigned short* __restrict__ nbrbf,
                                                const unsigned short* __restrict__ hbf,
                                                const unsigned short* __restrict__ WT2,
                                                const float* __restrict__ bias2,
                                                int Nn, float* __restrict__ out) {
    __shared__ __align__(16) unsigned short As[128][136];
    __shared__ __align__(16) unsigned short Bs[128][136];
    const int tid = threadIdx.x;
    const int wave = tid >> 6, lane = tid & 63;
    const int rowbase = blockIdx.x * 128;
    const int lq = lane >> 4, lr = lane & 15;

    f32x4 acc[2][8];
    #pragma unroll
    for (int mt = 0; mt < 2; ++mt)
        #pragma unroll
        for (int nt = 0; nt < 8; ++nt) acc[mt][nt] = (f32x4)0.f;

    for (int ph = 0; ph < 2; ++ph) {
        const unsigned short* A = ph ? hbf : nbrbf;
        const unsigned short* WT = WT2 + (size_t)ph * DH * DH;
        if (ph) __syncthreads();
        #pragma unroll
        for (int it = 0; it < 8; ++it) {
            int c = it * 256 + tid;
            int row = c >> 4, col = c & 15;
            int rg = rowbase + row; if (rg >= Nn) rg = Nn - 1;
            *(uint4*)&As[row][col * 8] = *(const uint4*)&A[(size_t)rg * DH + col * 8];
            *(uint4*)&Bs[row][col * 8] = *(const uint4*)&WT[(size_t)row * DH + col * 8];
        }
        __syncthreads();
        #pragma unroll
        for (int ks = 0; ks < 4; ++ks) {
            const int ko = ks * 32 + lq * 8;
            bf16x8 a0 = *(const bf16x8*)&As[wave * 32 + lr][ko];
            bf16x8 a1 = *(const bf16x8*)&As[wave * 32 + 16 + lr][ko];
            #pragma unroll
            for (int nt = 0; nt < 8; ++nt) {
                bf16x8 b = *(const bf16x8*)&Bs[nt * 16 + lr][ko];
                acc[0][nt] = __builtin_amdgcn_mfma_f32_16x16x32_bf16(a0, b, acc[0][nt], 0, 0, 0);
                acc[1][nt] = __builtin_amdgcn_mfma_f32_16x16x32_bf16(a1, b, acc[1][nt], 0, 0, 0);
            }
        }
    }

    float bv[8];
    #pragma unroll
    for (int nt = 0; nt < 8; ++nt) bv[nt] = bias2[nt * 16 + lr];
    #pragma unroll
    for (int mt = 0; mt < 2; ++mt)
        #pragma unroll
        for (int nt = 0; nt < 8; ++nt)
            #pragma unroll
            for (int reg = 0; reg < 4; ++reg) {
                int m = rowbase + wave * 32 + mt * 16 + lq * 4 + reg;
                if (m < Nn) out[(size_t)m * DH + nt * 16 + lr] = acc[mt][nt][reg] + bv[nt];
            }
}

extern "C" void kernel_launch(void* const* d_in, const int* in_sizes, int n_in,
                              void* d_out, int out_size, void* d_ws, size_t ws_size,
                              hipStream_t stream) {
    const float* x      = (const float*)d_in[0];
    const int*   eidx   = (const int*)d_in[1];
    // d_in[2] = edge_norm: unused by the reference computation
    const int*   etype  = (const int*)d_in[3];
    const float* basis  = (const float*)d_in[4];
    const float* comp   = (const float*)d_in[5];
    const float* root   = (const float*)d_in[6];
    const float* bias1  = (const float*)d_in[7];
    const float* wrel   = (const float*)d_in[8];
    const float* wroot2 = (const float*)d_in[9];
    const float* bias2  = (const float*)d_in[10];
    float* out = (float*)d_out;

    const int N = in_sizes[0] / DH;    // 40000
    const int E = in_sizes[3];         // 640000
    const int* srcA = eidx;
    const int* dstA = eidx + E;

    char* ws = (char*)d_ws;
    size_t off = 0;
    auto alloc = [&](size_t bytes) -> void* {
        void* p = (void*)(ws + off);
        off += (bytes + 255) & ~(size_t)255;
        return p;
    };
    int* deg           = (int*)alloc((size_t)N * 4);
    int* cursor        = (int*)alloc((size_t)N * 4);
    int* offsets       = (int*)alloc((size_t)(N + 1) * 4);
    int* partial       = (int*)alloc(256 * 4);
    unsigned* sorted   = (unsigned*)alloc((size_t)E * 4);
    unsigned short* wallT = (unsigned short*)alloc((size_t)(NR + 1) * DH * DH * 2);
    unsigned short* WT2   = (unsigned short*)alloc((size_t)2 * DH * DH * 2);
    unsigned short* Xbf   = (unsigned short*)alloc((size_t)N * DH * 2);
    unsigned short* xw    = (unsigned short*)alloc((size_t)NR * N * DH * 2);
    unsigned short* hb    = (unsigned short*)alloc((size_t)N * DH * 2);
    unsigned* hbf      = (unsigned*)alloc((size_t)N * (DH / 2) * 4);
    unsigned* nbrbf    = (unsigned*)alloc((size_t)N * (DH / 2) * 4);
    (void)ws_size; (void)n_in; (void)out_size;

    hipMemsetAsync(deg, 0, (size_t)N * 8, stream);  // deg + cursor (contiguous)

    k_cvtx<<<(N * DH / 4 + 255) / 256, 256, 0, stream>>>(x, Xbf, N * DH / 4);
    k_wprep<<<dim3(DH, NR + 3), DH, 0, stream>>>(comp, basis, root, wrel, wroot2, wallT, WT2);
    k_hist<<<(E + 255) / 256, 256, 0, stream>>>(dstA, E, deg);

    const int totn = N + 1;
    const int nsb = (totn + 1023) / 1024;
    k_scan1<<<nsb, 1024, 0, stream>>>(deg, N, totn, offsets, partial);
    k_scan2<<<1, 64, 0, stream>>>(partial, nsb);
    k_scan3<<<nsb, 1024, 0, stream>>>(offsets, partial, totn);
    k_scatter<<<(E + 255) / 256, 256, 0, stream>>>(srcA, dstA, etype, E, offsets, cursor, sorted);

    const int gx = (N + 127) / 128;
    k_gemm1m<<<dim3(gx, NR + 1), 256, 0, stream>>>(Xbf, wallT, bias1, N, xw, hb);
    k_agg1<<<(N * 64) / 256, 256, 0, stream>>>(offsets, sorted, (const unsigned*)xw,
                                               (const unsigned*)hb, N, hbf);
    k_agg2<<<(N * 64) / 256, 256, 0, stream>>>(offsets, sorted, hbf, N, nbrbf);
    k_gemm2m<<<gx, 256, 0, stream>>>((const unsigned short*)nbrbf, (const unsigned short*)hbf,
                                     WT2, bias2, N, out);
}

// Round 5
// 252.374 us; speedup vs baseline: 1.3320x; 1.0581x over previous
//
#include <hip/hip_runtime.h>
#include <stdint.h>

#define DH 128   // D_IN == H == 128
#define NB 30    // num bases
#define NR 8     // num relations

typedef short bf16x8 __attribute__((ext_vector_type(8)));   // 8 bf16 = 4 VGPRs
typedef float f32x4 __attribute__((ext_vector_type(4)));
typedef float f32x2 __attribute__((ext_vector_type(2)));

static __device__ __forceinline__ unsigned short f2bf(float f) {
    unsigned u = __float_as_uint(f);
    u += 0x7fffu + ((u >> 16) & 1u);   // round-to-nearest-even
    return (unsigned short)(u >> 16);
}
static __device__ __forceinline__ float bflo(unsigned u) { return __uint_as_float(u << 16); }
static __device__ __forceinline__ float bfhi(unsigned u) { return __uint_as_float(u & 0xffff0000u); }

// ---------- X fp32 -> bf16 ----------
__global__ __launch_bounds__(256) void k_cvtx(const float* __restrict__ x,
                                              unsigned short* __restrict__ xbf, int n4) {
    int i = blockIdx.x * blockDim.x + threadIdx.x;
    if (i < n4) {
        float4 v = ((const float4*)x)[i];
        ushort4 u;
        u.x = f2bf(v.x); u.y = f2bf(v.y); u.z = f2bf(v.z); u.w = f2bf(v.w);
        ((ushort4*)xbf)[i] = u;
    }
}

// ---------- weight prep (transposed bf16) ----------
__global__ __launch_bounds__(128) void k_wprep(const float* __restrict__ comp,
                                               const float* __restrict__ basis,
                                               const float* __restrict__ root,
                                               const float* __restrict__ wrel,
                                               const float* __restrict__ wroot2,
                                               unsigned short* __restrict__ wallT,
                                               unsigned short* __restrict__ WT2) {
    int o = threadIdx.x;    // 0..127
    int i = blockIdx.x;     // 0..127
    int y = blockIdx.y;     // 0..10
    if (y < NR) {
        float s = 0.f;
        #pragma unroll
        for (int b = 0; b < NB; ++b)
            s += comp[y * NB + b] * basis[((size_t)b * DH + i) * DH + o];
        wallT[((size_t)y * DH + o) * DH + i] = f2bf(s);
    } else if (y == NR) {
        wallT[((size_t)NR * DH + o) * DH + i] = f2bf(root[i * DH + o]);
    } else {
        const float* W = (y == NR + 2) ? wroot2 : wrel;
        WT2[((size_t)(y - NR - 1) * DH + o) * DH + i] = f2bf(W[i * DH + o]);
    }
}

// ---------- CSR build ----------
__global__ void k_hist(const int* __restrict__ dst, int E, int* __restrict__ deg) {
    int e = blockIdx.x * blockDim.x + threadIdx.x;
    if (e < E) atomicAdd(&deg[dst[e]], 1);
}

__global__ __launch_bounds__(1024) void k_scan1(const int* __restrict__ deg, int n, int total_n,
                                                int* __restrict__ offsets, int* __restrict__ partial) {
    __shared__ int s[1024];
    int tid = threadIdx.x;
    int i = blockIdx.x * 1024 + tid;
    int v = (i < n) ? deg[i] : 0;
    s[tid] = v;
    __syncthreads();
    for (int off = 1; off < 1024; off <<= 1) {
        int t = (tid >= off) ? s[tid - off] : 0;
        __syncthreads();
        s[tid] += t;
        __syncthreads();
    }
    if (i < total_n) offsets[i] = s[tid] - v;   // exclusive
    if (tid == 1023) partial[blockIdx.x] = s[1023];
}

__global__ void k_scan2(int* __restrict__ partial, int nb) {
    if (threadIdx.x == 0) {
        int run = 0;
        for (int b = 0; b < nb; ++b) { int t = partial[b]; partial[b] = run; run += t; }
    }
}

__global__ __launch_bounds__(1024) void k_scan3(int* __restrict__ offsets,
                                                const int* __restrict__ partial, int total_n) {
    int i = blockIdx.x * 1024 + threadIdx.x;
    if (i < total_n) offsets[i] += partial[blockIdx.x];
}

__global__ void k_scatter(const int* __restrict__ src, const int* __restrict__ dstA,
                          const int* __restrict__ etype, int E,
                          const int* __restrict__ offsets, int* __restrict__ cursor,
                          unsigned* __restrict__ sorted) {
    int e = blockIdx.x * blockDim.x + threadIdx.x;
    if (e >= E) return;
    int d = dstA[e];
    int pos = offsets[d] + atomicAdd(&cursor[d], 1);
    sorted[pos] = (unsigned)src[e] | ((unsigned)etype[e] << 17);  // src<2^17, type<8
}

// ---------- MFMA GEMM1: 128x128 tile, K=128, grid (ceil(N/128), 3) ----------
// blockIdx.y=g handles relations r = 3g..3g+2.
// r<8: xw8[r] = fp8(Xbf @ W_r). r==8: hb = bf16(Xbf @ root + bias1)
__global__ __launch_bounds__(256) void k_gemm1m(const unsigned short* __restrict__ Xbf,
                                                const unsigned short* __restrict__ wallT,
                                                const float* __restrict__ bias1,
                                                int Nn,
                                                unsigned* __restrict__ xw8,
                                                unsigned short* __restrict__ hb) {
    __shared__ __align__(16) unsigned short As[128][136];  // [m][k], +8 pad
    __shared__ __align__(16) unsigned short Bs[128][136];  // [n][k] / epilogue repack
    const int tid = threadIdx.x;
    const int wave = tid >> 6, lane = tid & 63;
    const int g = blockIdx.y;
    const int rowbase = blockIdx.x * 128;
    const int lq = lane >> 4, lr = lane & 15;

    // stage A once
    #pragma unroll
    for (int it = 0; it < 8; ++it) {
        int c = it * 256 + tid;
        int row = c >> 4, col = c & 15;
        int rg = rowbase + row; if (rg >= Nn) rg = Nn - 1;
        *(uint4*)&As[row][col * 8] = *(const uint4*)&Xbf[(size_t)rg * DH + col * 8];
    }

    for (int rr = 0; rr < 3; ++rr) {
        const int r = g * 3 + rr;
        const unsigned short* WT = wallT + (size_t)r * DH * DH;
        if (rr) __syncthreads();            // prior epilogue reads of Bs done
        #pragma unroll
        for (int it = 0; it < 8; ++it) {
            int c = it * 256 + tid;
            int row = c >> 4, col = c & 15;
            *(uint4*)&Bs[row][col * 8] = *(const uint4*)&WT[(size_t)row * DH + col * 8];
        }
        __syncthreads();                    // also covers As on first iter

        f32x4 acc[2][8];
        #pragma unroll
        for (int mt = 0; mt < 2; ++mt)
            #pragma unroll
            for (int nt = 0; nt < 8; ++nt) acc[mt][nt] = (f32x4)0.f;

        #pragma unroll
        for (int ks = 0; ks < 4; ++ks) {
            const int ko = ks * 32 + lq * 8;
            bf16x8 a0 = *(const bf16x8*)&As[wave * 32 + lr][ko];
            bf16x8 a1 = *(const bf16x8*)&As[wave * 32 + 16 + lr][ko];
            #pragma unroll
            for (int nt = 0; nt < 8; ++nt) {
                bf16x8 b = *(const bf16x8*)&Bs[nt * 16 + lr][ko];
                acc[0][nt] = __builtin_amdgcn_mfma_f32_16x16x32_bf16(a0, b, acc[0][nt], 0, 0, 0);
                acc[1][nt] = __builtin_amdgcn_mfma_f32_16x16x32_bf16(a1, b, acc[1][nt], 0, 0, 0);
            }
        }
        __syncthreads();                    // all MFMA reads of Bs done

        // repack C-layout -> canonical bf16 rows in Bs
        float bv[8];
        #pragma unroll
        for (int nt = 0; nt < 8; ++nt) bv[nt] = (r == NR) ? bias1[nt * 16 + lr] : 0.f;
        #pragma unroll
        for (int mt = 0; mt < 2; ++mt)
            #pragma unroll
            for (int nt = 0; nt < 8; ++nt)
                #pragma unroll
                for (int reg = 0; reg < 4; ++reg) {
                    int ml = wave * 32 + mt * 16 + lq * 4 + reg;   // own slab only
                    Bs[ml][nt * 16 + lr] = f2bf(acc[mt][nt][reg] + bv[nt]);
                }
        __syncthreads();

        if (r < NR) {
            unsigned* dst = xw8 + ((size_t)r * Nn + rowbase) * (DH / 4);
            #pragma unroll
            for (int it = 0; it < 8; ++it) {
                int c = it * 256 + tid;
                int row = c >> 4, col = c & 15;
                if (rowbase + row < Nn) {
                    uint4 q = *(uint4*)&Bs[row][col * 8];
                    uint2 o;
                    o.x = __builtin_amdgcn_cvt_pk_fp8_f32(bflo(q.x), bfhi(q.x), 0, false);
                    o.x = __builtin_amdgcn_cvt_pk_fp8_f32(bflo(q.y), bfhi(q.y), o.x, true);
                    o.y = __builtin_amdgcn_cvt_pk_fp8_f32(bflo(q.z), bfhi(q.z), 0, false);
                    o.y = __builtin_amdgcn_cvt_pk_fp8_f32(bflo(q.w), bfhi(q.w), o.y, true);
                    *(uint2*)&dst[(size_t)row * (DH / 4) + col * 2] = o;
                }
            }
        } else {
            #pragma unroll
            for (int it = 0; it < 8; ++it) {
                int c = it * 256 + tid;
                int row = c >> 4, col = c & 15;
                if (rowbase + row < Nn)
                    *(uint4*)&hb[((size_t)(rowbase + row)) * DH + col * 8] = *(uint4*)&Bs[row][col * 8];
            }
        }
    }
}

// ---------- pass-1 aggregation: one wave per dst, fp8 gather, 2 edges/step x8 ----------
// hbf[dst] = bf16( hb[dst] + (1/deg) * sum_e xw8[type_e][src_e] )
__global__ __launch_bounds__(256) void k_agg1(const int* __restrict__ offsets,
                                              const unsigned* __restrict__ sorted,
                                              const unsigned* __restrict__ xw8,
                                              const unsigned* __restrict__ hb32,
                                              int Nn, unsigned* __restrict__ hbf) {
    int w = (blockIdx.x * blockDim.x + threadIdx.x) >> 6;
    if (w >= Nn) return;
    int lane = threadIdx.x & 63;
    int half = lane >> 5, sub = lane & 31;    // half-wave h reads edge 2j+h, 4 features/lane
    int s = offsets[w], e = offsets[w + 1];
    float a0 = 0.f, a1 = 0.f, a2 = 0.f, a3 = 0.f;
    for (int p = s; p < e; p += 16) {
        unsigned pk[8]; float m[8];
        #pragma unroll
        for (int j = 0; j < 8; ++j) {
            int q = p + 2 * j + half; bool v = q < e;
            pk[j] = sorted[v ? q : e - 1];
            m[j] = v ? 1.f : 0.f;
        }
        unsigned u[8];
        #pragma unroll
        for (int j = 0; j < 8; ++j)
            u[j] = xw8[((size_t)(pk[j] >> 17) * Nn + (pk[j] & 0x1FFFFu)) * 32 + sub];
        #pragma unroll
        for (int j = 0; j < 8; ++j) {
            f32x2 lo = __builtin_amdgcn_cvt_pk_f32_fp8(u[j], false);
            f32x2 hi = __builtin_amdgcn_cvt_pk_f32_fp8(u[j], true);
            a0 = fmaf(m[j], lo.x, a0);
            a1 = fmaf(m[j], lo.y, a1);
            a2 = fmaf(m[j], hi.x, a2);
            a3 = fmaf(m[j], hi.y, a3);
        }
    }
    a0 += __shfl_xor(a0, 32, 64);
    a1 += __shfl_xor(a1, 32, 64);
    a2 += __shfl_xor(a2, 32, 64);
    a3 += __shfl_xor(a3, 32, 64);
    if (half == 0) {
        float invd = 1.0f / fmaxf((float)(e - s), 1.0f);
        uint2 hv = *(const uint2*)&hb32[(size_t)w * 64 + sub * 2];
        float h0 = bflo(hv.x) + a0 * invd;
        float h1 = bfhi(hv.x) + a1 * invd;
        float h2 = bflo(hv.y) + a2 * invd;
        float h3 = bfhi(hv.y) + a3 * invd;
        uint2 o;
        o.x = (unsigned)f2bf(h0) | ((unsigned)f2bf(h1) << 16);
        o.y = (unsigned)f2bf(h2) | ((unsigned)f2bf(h3) << 16);
        *(uint2*)&hbf[(size_t)w * 64 + sub * 2] = o;
    }
}

// ---------- pass-2 aggregation: nbrbf[dst] = bf16( sum_e hbf[src_e] ) ----------
__global__ __launch_bounds__(256) void k_agg2(const int* __restrict__ offsets,
                                              const unsigned* __restrict__ sorted,
                                              const unsigned* __restrict__ hbf32,
                                              int Nn, unsigned* __restrict__ nbrbf) {
    int w = (blockIdx.x * blockDim.x + threadIdx.x) >> 6;
    if (w >= Nn) return;
    int lane = threadIdx.x & 63;
    int s = offsets[w], e = offsets[w + 1];
    float ax = 0.f, ay = 0.f;
    for (int p = s; p < e; p += 16) {
        unsigned pk[16]; float m[16];
        #pragma unroll
        for (int j = 0; j < 16; ++j) {
            int q = p + j; bool v = q < e;
            pk[j] = sorted[v ? q : e - 1];
            m[j] = v ? 1.f : 0.f;
        }
        unsigned u[16];
        #pragma unroll
        for (int j = 0; j < 16; ++j)
            u[j] = hbf32[(size_t)(pk[j] & 0x1FFFFu) * 64 + lane];
        #pragma unroll
        for (int j = 0; j < 16; ++j) {
            ax = fmaf(m[j], __uint_as_float(u[j] << 16), ax);
            ay = fmaf(m[j], __uint_as_float(u[j] & 0xffff0000u), ay);
        }
    }
    nbrbf[(size_t)w * 64 + lane] = (unsigned)f2bf(ax) | ((unsigned)f2bf(ay) << 16);
}

// ---------- MFMA GEMM2: out = nbr@w_rel + h@w_root2 + bias2 (K=256 in 2 phases) ----------
__global__ __launch_bounds__(256) void k_gemm2m(const unsigned short* __restrict__ nbrbf,
                                                const unsigned short* __restrict__ hbf,
                                                const unsigned short* __restrict__ WT2,
                                                const float* __restrict__ bias2,
                                                int Nn, float* __restrict__ out) {
    __shared__ __align__(16) unsigned short As[128][136];
    __shared__ __align__(16) unsigned short Bs[128][136];
    const int tid = threadIdx.x;
    const int wave = tid >> 6, lane = tid & 63;
    const int rowbase = blockIdx.x * 128;
    const int lq = lane >> 4, lr = lane & 15;

    f32x4 acc[2][8];
    #pragma unroll
    for (int mt = 0; mt < 2; ++mt)
        #pragma unroll
        for (int nt = 0; nt < 8; ++nt) acc[mt][nt] = (f32x4)0.f;

    for (int ph = 0; ph < 2; ++ph) {
        const unsigned short* A = ph ? hbf : nbrbf;
        const unsigned short* WT = WT2 + (size_t)ph * DH * DH;
        if (ph) __syncthreads();
        #pragma unroll
        for (int it = 0; it < 8; ++it) {
            int c = it * 256 + tid;
            int row = c >> 4, col = c & 15;
            int rg = rowbase + row; if (rg >= Nn) rg = Nn - 1;
            *(uint4*)&As[row][col * 8] = *(const uint4*)&A[(size_t)rg * DH + col * 8];
            *(uint4*)&Bs[row][col * 8] = *(const uint4*)&WT[(size_t)row * DH + col * 8];
        }
        __syncthreads();
        #pragma unroll
        for (int ks = 0; ks < 4; ++ks) {
            const int ko = ks * 32 + lq * 8;
            bf16x8 a0 = *(const bf16x8*)&As[wave * 32 + lr][ko];
            bf16x8 a1 = *(const bf16x8*)&As[wave * 32 + 16 + lr][ko];
            #pragma unroll
            for (int nt = 0; nt < 8; ++nt) {
                bf16x8 b = *(const bf16x8*)&Bs[nt * 16 + lr][ko];
                acc[0][nt] = __builtin_amdgcn_mfma_f32_16x16x32_bf16(a0, b, acc[0][nt], 0, 0, 0);
                acc[1][nt] = __builtin_amdgcn_mfma_f32_16x16x32_bf16(a1, b, acc[1][nt], 0, 0, 0);
            }
        }
    }

    float bv[8];
    #pragma unroll
    for (int nt = 0; nt < 8; ++nt) bv[nt] = bias2[nt * 16 + lr];
    #pragma unroll
    for (int mt = 0; mt < 2; ++mt)
        #pragma unroll
        for (int nt = 0; nt < 8; ++nt)
            #pragma unroll
            for (int reg = 0; reg < 4; ++reg) {
                int m = rowbase + wave * 32 + mt * 16 + lq * 4 + reg;
                if (m < Nn) out[(size_t)m * DH + nt * 16 + lr] = acc[mt][nt][reg] + bv[nt];
            }
}

extern "C" void kernel_launch(void* const* d_in, const int* in_sizes, int n_in,
                              void* d_out, int out_size, void* d_ws, size_t ws_size,
                              hipStream_t stream) {
    const float* x      = (const float*)d_in[0];
    const int*   eidx   = (const int*)d_in[1];
    // d_in[2] = edge_norm: unused by the reference computation
    const int*   etype  = (const int*)d_in[3];
    const float* basis  = (const float*)d_in[4];
    const float* comp   = (const float*)d_in[5];
    const float* root   = (const float*)d_in[6];
    const float* bias1  = (const float*)d_in[7];
    const float* wrel   = (const float*)d_in[8];
    const float* wroot2 = (const float*)d_in[9];
    const float* bias2  = (const float*)d_in[10];
    float* out = (float*)d_out;

    const int N = in_sizes[0] / DH;    // 40000
    const int E = in_sizes[3];         // 640000
    const int* srcA = eidx;
    const int* dstA = eidx + E;

    char* ws = (char*)d_ws;
    size_t off = 0;
    auto alloc = [&](size_t bytes) -> void* {
        void* p = (void*)(ws + off);
        off += (bytes + 255) & ~(size_t)255;
        return p;
    };
    int* deg           = (int*)alloc((size_t)N * 4);
    int* cursor        = (int*)alloc((size_t)N * 4);
    int* offsets       = (int*)alloc((size_t)(N + 1) * 4);
    int* partial       = (int*)alloc(256 * 4);
    unsigned* sorted   = (unsigned*)alloc((size_t)E * 4);
    unsigned short* wallT = (unsigned short*)alloc((size_t)(NR + 1) * DH * DH * 2);
    unsigned short* WT2   = (unsigned short*)alloc((size_t)2 * DH * DH * 2);
    unsigned short* Xbf   = (unsigned short*)alloc((size_t)N * DH * 2);
    unsigned* xw8      = (unsigned*)alloc((size_t)NR * N * DH);       // fp8 e4m3
    unsigned short* hb = (unsigned short*)alloc((size_t)N * DH * 2);
    unsigned* hbf      = (unsigned*)alloc((size_t)N * (DH / 2) * 4);
    unsigned* nbrbf    = (unsigned*)alloc((size_t)N * (DH / 2) * 4);
    (void)ws_size; (void)n_in; (void)out_size;

    hipMemsetAsync(deg, 0, (size_t)N * 8, stream);  // deg + cursor (contiguous)

    k_cvtx<<<(N * DH / 4 + 255) / 256, 256, 0, stream>>>(x, Xbf, N * DH / 4);
    k_wprep<<<dim3(DH, NR + 3), DH, 0, stream>>>(comp, basis, root, wrel, wroot2, wallT, WT2);
    k_hist<<<(E + 255) / 256, 256, 0, stream>>>(dstA, E, deg);

    const int totn = N + 1;
    const int nsb = (totn + 1023) / 1024;
    k_scan1<<<nsb, 1024, 0, stream>>>(deg, N, totn, offsets, partial);
    k_scan2<<<1, 64, 0, stream>>>(partial, nsb);
    k_scan3<<<nsb, 1024, 0, stream>>>(offsets, partial, totn);
    k_scatter<<<(E + 255) / 256, 256, 0, stream>>>(srcA, dstA, etype, E, offsets, cursor, sorted);

    const int gx = (N + 127) / 128;
    k_gemm1m<<<dim3(gx, 3), 256, 0, stream>>>(Xbf, wallT, bias1, N, xw8, hb);
    k_agg1<<<(N * 64) / 256, 256, 0, stream>>>(offsets, sorted, xw8,
                                               (const unsigned*)hb, N, hbf);
    k_agg2<<<(N * 64) / 256, 256, 0, stream>>>(offsets, sorted, hbf, N, nbrbf);
    k_gemm2m<<<gx, 256, 0, stream>>>((const unsigned short*)nbrbf, (const unsigned short*)hbf,
                                     WT2, bias2, N, out);
}